// Round 1
// baseline (314.711 us; speedup 1.0000x reference)
//
#include <hip/hip_runtime.h>

typedef unsigned short u16;
typedef unsigned int   u32;
typedef float f32x4 __attribute__((ext_vector_type(4)));
typedef __bf16 bf16x8 __attribute__((ext_vector_type(8)));

__device__ __forceinline__ u16 f2bf(float f){
  u32 u = __float_as_uint(f);
  u += 0x7fffu + ((u >> 16) & 1u);          // RNE
  return (u16)(u >> 16);
}

// ---------------- weight conversion: fp32->bf16, sigs->ternary bf16 ----------------
__global__ __launch_bounds__(256) void convert_kernel(
    const float* __restrict__ qw, const float* __restrict__ ow,
    const float* __restrict__ sg,
    u16* __restrict__ qwb, u16* __restrict__ owb, u16* __restrict__ sgb){
  int i = blockIdx.x * 256 + threadIdx.x;   // 1,048,576 elements each
  qwb[i] = f2bf(qw[i]);
  owb[i] = f2bf(ow[i]);
  float s = sg[i];
  float t = (s > 0.3f) ? 1.0f : ((s < -0.3f) ? -1.0f : 0.0f);
  sgb[i] = f2bf(t);                          // {-1,0,1} exact in bf16
}

// ---------------- LayerNorm: one block per token ----------------
__global__ __launch_bounds__(256) void ln_kernel(
    const float* __restrict__ x, const float* __restrict__ g,
    const float* __restrict__ b, u16* __restrict__ xn){
  const int t = blockIdx.x, tid = threadIdx.x;
  f32x4 v = *(const f32x4*)(x + (size_t)t * 1024 + tid * 4);
  float s  = v[0] + v[1] + v[2] + v[3];
  float ss = v[0]*v[0] + v[1]*v[1] + v[2]*v[2] + v[3]*v[3];
  for (int off = 32; off; off >>= 1){
    s  += __shfl_down(s, off);
    ss += __shfl_down(ss, off);
  }
  __shared__ float red[8];
  int w = tid >> 6;
  if ((tid & 63) == 0){ red[w] = s; red[4 + w] = ss; }
  __syncthreads();
  s  = red[0] + red[1] + red[2] + red[3];
  ss = red[4] + red[5] + red[6] + red[7];
  float mean = s * (1.0f / 1024.0f);
  float var  = ss * (1.0f / 1024.0f) - mean * mean;   // jnp.var (ddof=0)
  float rs   = rsqrtf(var + 1e-5f);
  f32x4 gv = *(const f32x4*)(g + tid * 4);
  f32x4 bv = *(const f32x4*)(b + tid * 4);
  float y0 = (v[0]-mean)*rs*gv[0]+bv[0];
  float y1 = (v[1]-mean)*rs*gv[1]+bv[1];
  float y2 = (v[2]-mean)*rs*gv[2]+bv[2];
  float y3 = (v[3]-mean)*rs*gv[3]+bv[3];
  uint2 pk;
  pk.x = (u32)f2bf(y0) | ((u32)f2bf(y1) << 16);
  pk.y = (u32)f2bf(y2) | ((u32)f2bf(y3) << 16);
  *(uint2*)(xn + (size_t)t * 1024 + tid * 4) = pk;
}

// ---------------- bf16 MFMA GEMM: C[m,n] = sum_k A[m,k]*B[n,k] (+epilogue) ----------------
// M=8192, N=1024, K=1024. 128x128 tile, 4 waves in 2x2, each wave 64x64 (4x4 MFMA 16x16x32).
// mode 0: outb[m,n] = bf16(C + bias[n]);  mode 1: outf[m,n] = C + bias[n] + resid[m,n]
__global__ __launch_bounds__(256, 2) void gemm_bt(
    const u16* __restrict__ A, const u16* __restrict__ B,
    const float* __restrict__ bias, const float* __restrict__ resid,
    float* __restrict__ outf, u16* __restrict__ outb, int mode){
  __shared__ u16 As[128 * 72];      // +8 pad: 2-way LDS aliasing only (free)
  __shared__ u16 Bs[128 * 72];
  const int tid = threadIdx.x;
  const int m0 = blockIdx.y * 128, n0 = blockIdx.x * 128;
  const int w = tid >> 6, lane = tid & 63, lm = lane & 15, quad = lane >> 4;
  const int wm = (w & 1) * 64, wn = (w >> 1) * 64;
  const f32x4 fz = {0.f, 0.f, 0.f, 0.f};
  f32x4 acc[4][4];
  #pragma unroll
  for (int i = 0; i < 4; ++i)
    #pragma unroll
    for (int j = 0; j < 4; ++j) acc[i][j] = fz;

  for (int kt = 0; kt < 16; ++kt){
    #pragma unroll
    for (int i = 0; i < 4; ++i){
      int c = tid + i * 256;
      int row = c >> 3, kc = (c & 7) * 8;
      *(uint4*)(&As[row * 72 + kc]) = *(const uint4*)(&A[(size_t)(m0 + row) * 1024 + kt * 64 + kc]);
      *(uint4*)(&Bs[row * 72 + kc]) = *(const uint4*)(&B[(size_t)(n0 + row) * 1024 + kt * 64 + kc]);
    }
    __syncthreads();
    #pragma unroll
    for (int kk = 0; kk < 64; kk += 32){
      bf16x8 afr[4], bfr[4];
      #pragma unroll
      for (int i = 0; i < 4; ++i)
        afr[i] = *(const bf16x8*)(&As[(wm + i * 16 + lm) * 72 + kk + quad * 8]);
      #pragma unroll
      for (int j = 0; j < 4; ++j)
        bfr[j] = *(const bf16x8*)(&Bs[(wn + j * 16 + lm) * 72 + kk + quad * 8]);
      #pragma unroll
      for (int i = 0; i < 4; ++i)
        #pragma unroll
        for (int j = 0; j < 4; ++j)
          acc[i][j] = __builtin_amdgcn_mfma_f32_16x16x32_bf16(afr[i], bfr[j], acc[i][j], 0, 0, 0);
    }
    __syncthreads();
  }

  #pragma unroll
  for (int i = 0; i < 4; ++i){
    #pragma unroll
    for (int r = 0; r < 4; ++r){
      int grow = m0 + wm + i * 16 + quad * 4 + r;
      #pragma unroll
      for (int j = 0; j < 4; ++j){
        int gcol = n0 + wn + j * 16 + lm;
        float v = acc[i][j][r] + bias[gcol];
        if (mode){
          v += resid[(size_t)grow * 1024 + gcol];
          outf[(size_t)grow * 1024 + gcol] = v;
        } else {
          outb[(size_t)grow * 1024 + gcol] = f2bf(v);
        }
      }
    }
  }
}

// ---------------- fused scores + top2 + softmax + gather ----------------
// block = 16 tokens x 1 head; 4 waves, wave w scans slots [w*256, w*256+256)
__global__ __launch_bounds__(256) void route_kernel(
    const u16* __restrict__ q, const u16* __restrict__ sig,
    const float* __restrict__ V, const float* __restrict__ temp,
    u16* __restrict__ rd){
  const int h = blockIdx.y;
  const int t0 = blockIdx.x * 16;
  const int tid = threadIdx.x, w = tid >> 6, lane = tid & 63;
  const int lm = lane & 15, quad = lane >> 4;

  const u16* qrow = q + (size_t)(t0 + lm) * 1024 + h * 64;
  bf16x8 a0 = *(const bf16x8*)(qrow + quad * 8);
  bf16x8 a1 = *(const bf16x8*)(qrow + 32 + quad * 8);

  float v1[4], v2[4]; int j1[4], j2[4];
  #pragma unroll
  for (int r = 0; r < 4; ++r){ v1[r] = -3e38f; v2[r] = -3e38f; j1[r] = 0; j2[r] = 0; }

  const u16* sigh = sig + (size_t)h * 65536;
  for (int sb = w * 256, e = w * 256 + 256; sb < e; sb += 16){
    const u16* srow = sigh + (size_t)(sb + lm) * 64;
    bf16x8 b0 = *(const bf16x8*)(srow + quad * 8);
    bf16x8 b1 = *(const bf16x8*)(srow + 32 + quad * 8);
    f32x4 acc = {0.f, 0.f, 0.f, 0.f};
    acc = __builtin_amdgcn_mfma_f32_16x16x32_bf16(a0, b0, acc, 0, 0, 0);
    acc = __builtin_amdgcn_mfma_f32_16x16x32_bf16(a1, b1, acc, 0, 0, 0);
    int sidx = sb + lm;
    #pragma unroll
    for (int r = 0; r < 4; ++r){
      float v = acc[r];
      bool g1 = v > v1[r];
      bool g2 = v > v2[r];
      float nv2 = g1 ? v1[r] : (g2 ? v : v2[r]);
      int   nj2 = g1 ? j1[r] : (g2 ? sidx : j2[r]);
      v2[r] = nv2; j2[r] = nj2;
      v1[r] = g1 ? v : v1[r];
      j1[r] = g1 ? sidx : j1[r];
    }
  }
  // butterfly merge across the 16 columns (lanes sharing the same 4 token rows)
  #pragma unroll
  for (int off = 1; off < 16; off <<= 1){
    #pragma unroll
    for (int r = 0; r < 4; ++r){
      float ov1 = __shfl_xor(v1[r], off);
      int   oj1 = __shfl_xor(j1[r], off);
      float ov2 = __shfl_xor(v2[r], off);
      int   oj2 = __shfl_xor(j2[r], off);
      bool gt = ov1 > v1[r];
      float ca = gt ? v1[r] : ov1; int cja = gt ? j1[r] : oj1;
      float cb = gt ? ov2  : v2[r]; int cjb = gt ? oj2  : j2[r];
      v1[r] = gt ? ov1 : v1[r];  j1[r] = gt ? oj1 : j1[r];
      bool gb = cb > ca;
      v2[r] = gb ? cb : ca;  j2[r] = gb ? cjb : cja;
    }
  }
  __shared__ float sv1[4][16], sv2[4][16];
  __shared__ int   si1[4][16], si2[4][16];
  if (lm == 0){
    #pragma unroll
    for (int r = 0; r < 4; ++r){
      sv1[w][quad * 4 + r] = v1[r]; sv2[w][quad * 4 + r] = v2[r];
      si1[w][quad * 4 + r] = j1[r]; si2[w][quad * 4 + r] = j2[r];
    }
  }
  __syncthreads();
  __shared__ float w1s[16], w2s[16];
  __shared__ int   f1[16], f2[16];
  if (tid < 16){
    float V1 = sv1[0][tid], V2 = sv2[0][tid];
    int   I1 = si1[0][tid], I2 = si2[0][tid];
    #pragma unroll
    for (int ww = 1; ww < 4; ++ww){
      float ov1 = sv1[ww][tid], ov2 = sv2[ww][tid];
      int   oj1 = si1[ww][tid], oj2 = si2[ww][tid];
      bool gt = ov1 > V1;
      float ca = gt ? V1 : ov1; int cja = gt ? I1 : oj1;
      float cb = gt ? ov2 : V2; int cjb = gt ? oj2 : I2;
      if (gt){ V1 = ov1; I1 = oj1; }
      bool gb = cb > ca;
      V2 = gb ? cb : ca; I2 = gb ? cjb : cja;
    }
    float tsc = 1.0f / (temp[0] * 8.0f);     // 1/(temperature*sqrt(64))
    float ex = expf((V2 - V1) * tsc);        // <= 1, stable
    float iw = 1.0f / (1.0f + ex);
    w1s[tid] = iw; w2s[tid] = ex * iw;
    f1[tid] = I1;  f2[tid] = I2;
  }
  __syncthreads();
  // gather: 16 tokens x 64 dims, 4 dims/thread
  int tl = tid >> 4, d0 = (tid & 15) * 4;
  const float* va = V + ((size_t)h * 1024 + f1[tl]) * 64 + d0;
  const float* vb = V + ((size_t)h * 1024 + f2[tl]) * 64 + d0;
  float W1 = w1s[tl], W2 = w2s[tl];
  uint2 pk;
  pk.x = (u32)f2bf(W1 * va[0] + W2 * vb[0]) | ((u32)f2bf(W1 * va[1] + W2 * vb[1]) << 16);
  pk.y = (u32)f2bf(W1 * va[2] + W2 * vb[2]) | ((u32)f2bf(W1 * va[3] + W2 * vb[3]) << 16);
  *(uint2*)(&rd[(size_t)(t0 + tl) * 1024 + h * 64 + d0]) = pk;
}

extern "C" void kernel_launch(void* const* d_in, const int* in_sizes, int n_in,
                              void* d_out, int out_size, void* d_ws, size_t ws_size,
                              hipStream_t stream){
  const float* x    = (const float*)d_in[0];
  const float* lng  = (const float*)d_in[1];
  const float* lnb  = (const float*)d_in[2];
  const float* qw   = (const float*)d_in[3];
  const float* qb   = (const float*)d_in[4];
  const float* sig  = (const float*)d_in[5];
  const float* sv   = (const float*)d_in[6];
  const float* ow   = (const float*)d_in[7];
  const float* ob   = (const float*)d_in[8];
  const float* temp = (const float*)d_in[9];
  float* out = (float*)d_out;

  char* ws = (char*)d_ws;
  u16* xn   = (u16*)(ws);                                  // 16 MiB  (x_norm bf16; reused as `read`)
  u16* qwb  = (u16*)(ws + 16777216);                       //  2 MiB
  u16* owb  = (u16*)(ws + 16777216 + 2097152);             //  2 MiB
  u16* sgb  = (u16*)(ws + 16777216 + 2 * 2097152);         //  2 MiB
  u16* qb16 = (u16*)(ws + 16777216 + 3 * 2097152);         // 16 MiB  (q bf16)
  u16* rdb  = xn;                                          // alias: x_norm dead after GEMM1

  convert_kernel<<<4096, 256, 0, stream>>>(qw, ow, sig, qwb, owb, sgb);
  ln_kernel<<<8192, 256, 0, stream>>>(x, lng, lnb, xn);
  gemm_bt<<<dim3(8, 64), 256, 0, stream>>>(xn, qwb, qb, nullptr, nullptr, qb16, 0);
  route_kernel<<<dim3(512, 16), 256, 0, stream>>>(qb16, sgb, sv, temp, rdb);
  gemm_bt<<<dim3(8, 64), 256, 0, stream>>>(rdb, owb, ob, x, out, nullptr, 1);
}

// Round 2
// 224.520 us; speedup vs baseline: 1.4017x; 1.4017x over previous
//
#include <hip/hip_runtime.h>

typedef unsigned short u16;
typedef unsigned int   u32;
typedef float f32x4 __attribute__((ext_vector_type(4)));
typedef __bf16 bf16x8 __attribute__((ext_vector_type(8)));

__device__ __forceinline__ u16 f2bf(float f){
  u32 u = __float_as_uint(f);
  u += 0x7fffu + ((u >> 16) & 1u);          // RNE
  return (u16)(u >> 16);
}

// async global->LDS, 16B per lane; LDS dest is wave-uniform base + lane*16
__device__ __forceinline__ void gld16(const void* g, void* l){
  __builtin_amdgcn_global_load_lds((const __attribute__((address_space(1))) u32*)g,
                                   (__attribute__((address_space(3))) u32*)l, 16, 0, 0);
}

// ---------------- weight conversion: fp32->bf16, sigs->ternary bf16 ----------------
__global__ __launch_bounds__(256) void convert_kernel(
    const float* __restrict__ qw, const float* __restrict__ ow,
    const float* __restrict__ sg,
    u16* __restrict__ qwb, u16* __restrict__ owb, u16* __restrict__ sgb){
  int i = blockIdx.x * 256 + threadIdx.x;   // 1,048,576 elements each
  qwb[i] = f2bf(qw[i]);
  owb[i] = f2bf(ow[i]);
  float s = sg[i];
  float t = (s > 0.3f) ? 1.0f : ((s < -0.3f) ? -1.0f : 0.0f);
  sgb[i] = f2bf(t);                          // {-1,0,1} exact in bf16
}

// ---------------- LayerNorm: one block per token ----------------
__global__ __launch_bounds__(256) void ln_kernel(
    const float* __restrict__ x, const float* __restrict__ g,
    const float* __restrict__ b, u16* __restrict__ xn){
  const int t = blockIdx.x, tid = threadIdx.x;
  f32x4 v = *(const f32x4*)(x + (size_t)t * 1024 + tid * 4);
  float s  = v[0] + v[1] + v[2] + v[3];
  float ss = v[0]*v[0] + v[1]*v[1] + v[2]*v[2] + v[3]*v[3];
  for (int off = 32; off; off >>= 1){
    s  += __shfl_down(s, off);
    ss += __shfl_down(ss, off);
  }
  __shared__ float red[8];
  int w = tid >> 6;
  if ((tid & 63) == 0){ red[w] = s; red[4 + w] = ss; }
  __syncthreads();
  s  = red[0] + red[1] + red[2] + red[3];
  ss = red[4] + red[5] + red[6] + red[7];
  float mean = s * (1.0f / 1024.0f);
  float var  = ss * (1.0f / 1024.0f) - mean * mean;   // jnp.var (ddof=0)
  float rs   = rsqrtf(var + 1e-5f);
  f32x4 gv = *(const f32x4*)(g + tid * 4);
  f32x4 bv = *(const f32x4*)(b + tid * 4);
  float y0 = (v[0]-mean)*rs*gv[0]+bv[0];
  float y1 = (v[1]-mean)*rs*gv[1]+bv[1];
  float y2 = (v[2]-mean)*rs*gv[2]+bv[2];
  float y3 = (v[3]-mean)*rs*gv[3]+bv[3];
  uint2 pk;
  pk.x = (u32)f2bf(y0) | ((u32)f2bf(y1) << 16);
  pk.y = (u32)f2bf(y2) | ((u32)f2bf(y3) << 16);
  *(uint2*)(xn + (size_t)t * 1024 + tid * 4) = pk;
}

// ---------------- bf16 MFMA GEMM: C[m,n] = sum_k A[m,k]*B[n,k] (+epilogue) ----------------
// M=8192, N=1024, K=1024. 128x128 tile, 4 waves in 2x2, each wave 64x64 (4x4 MFMA 16x16x32).
// LDS unpadded 64-u16 stride, XOR-swizzled: chunk g (16B) of row s lives at position g^(s&7).
// Staged via global_load_lds (lane-linear dest); swizzle applied on the SOURCE address.
// mode 0: outb[m,n] = bf16(C + bias[n]);  mode 1: outf[m,n] = C + bias[n] + resid[m,n]
__global__ __launch_bounds__(256, 2) void gemm_bt(
    const u16* __restrict__ A, const u16* __restrict__ B,
    const float* __restrict__ bias, const float* __restrict__ resid,
    float* __restrict__ outf, u16* __restrict__ outb, int mode){
  __shared__ u16 As[128 * 64];      // 16 KB
  __shared__ u16 Bs[128 * 64];
  const int tid = threadIdx.x;
  const int m0 = blockIdx.y * 128, n0 = blockIdx.x * 128;
  const int w = tid >> 6, lane = tid & 63, lm = lane & 15, quad = lane >> 4;
  const int wm = (w & 1) * 64, wn = (w >> 1) * 64;
  const int lr = lane >> 3;                 // row-within-8 of this lane's staging chunk
  const int lg = (lane & 7) ^ lr;           // swizzled source chunk id
  const f32x4 fz = {0.f, 0.f, 0.f, 0.f};
  f32x4 acc[4][4];
  #pragma unroll
  for (int i = 0; i < 4; ++i)
    #pragma unroll
    for (int j = 0; j < 4; ++j) acc[i][j] = fz;

  const u16* gA = A + (size_t)(m0 + w * 32 + lr) * 1024 + lg * 8;
  const u16* gB = B + (size_t)(n0 + w * 32 + lr) * 1024 + lg * 8;
  u16* lA = &As[(w * 32) * 64];             // wave-uniform LDS bases
  u16* lB = &Bs[(w * 32) * 64];
  const int sw = lm & 7;

  for (int kt = 0; kt < 16; ++kt){
    #pragma unroll
    for (int sub = 0; sub < 4; ++sub){
      gld16(gA + (size_t)(sub * 8) * 1024 + kt * 64, lA + sub * 8 * 64);
      gld16(gB + (size_t)(sub * 8) * 1024 + kt * 64, lB + sub * 8 * 64);
    }
    __syncthreads();
    #pragma unroll
    for (int kk = 0; kk < 2; ++kk){
      const int ch = ((quad + kk * 4) ^ sw) * 8;   // swizzled chunk offset (u16)
      bf16x8 afr[4], bfr[4];
      #pragma unroll
      for (int i = 0; i < 4; ++i)
        afr[i] = *(const bf16x8*)(&As[(wm + i * 16 + lm) * 64 + ch]);
      #pragma unroll
      for (int j = 0; j < 4; ++j)
        bfr[j] = *(const bf16x8*)(&Bs[(wn + j * 16 + lm) * 64 + ch]);
      #pragma unroll
      for (int i = 0; i < 4; ++i)
        #pragma unroll
        for (int j = 0; j < 4; ++j)
          acc[i][j] = __builtin_amdgcn_mfma_f32_16x16x32_bf16(afr[i], bfr[j], acc[i][j], 0, 0, 0);
    }
    __syncthreads();
  }

  #pragma unroll
  for (int i = 0; i < 4; ++i){
    #pragma unroll
    for (int r = 0; r < 4; ++r){
      int grow = m0 + wm + i * 16 + quad * 4 + r;
      #pragma unroll
      for (int j = 0; j < 4; ++j){
        int gcol = n0 + wn + j * 16 + lm;
        float v = acc[i][j][r] + bias[gcol];
        if (mode){
          v += resid[(size_t)grow * 1024 + gcol];
          outf[(size_t)grow * 1024 + gcol] = v;
        } else {
          outb[(size_t)grow * 1024 + gcol] = f2bf(v);
        }
      }
    }
  }
}

// ---------------- fused scores + top2 + softmax + gather ----------------
// block = 64 tokens x 1 head; 4 waves, wave w owns tokens [w*16, w*16+16).
// sig tile (64 slots x 64 dims, 8KB) staged in LDS (double-buffered, XOR-swizzled),
// shared by all 4 waves. Each wave scans all 1024 slots for its tokens.
__global__ __launch_bounds__(256) void route_kernel(
    const u16* __restrict__ q, const u16* __restrict__ sig,
    const float* __restrict__ V, const float* __restrict__ temp,
    u16* __restrict__ rd){
  const int h = blockIdx.y;
  const int t0 = blockIdx.x * 64;
  const int tid = threadIdx.x, w = tid >> 6, lane = tid & 63;
  const int lm = lane & 15, quad = lane >> 4;

  __shared__ u16 sbuf[2][64 * 64];          // 2 x 8 KB, swizzled
  __shared__ float fw1[64], fw2[64];
  __shared__ int   fi1[64], fi2[64];

  // q fragment: A[m][k] with m=lm -> token t0 + w*16 + lm, k = quad*8+j
  const u16* qrow = q + (size_t)(t0 + w * 16 + lm) * 1024 + h * 64;
  bf16x8 a0 = *(const bf16x8*)(qrow + quad * 8);
  bf16x8 a1 = *(const bf16x8*)(qrow + 32 + quad * 8);

  const u16* sigh = sig + (size_t)h * 65536;

  // stage tile t into sbuf[b]: thread handles 16B chunks c = tid, tid+256
  // chunk c: slot s=c>>3, lds-pos gl=c&7 holds source chunk g = gl^(s&7)
  auto stage = [&](int t, int b){
    #pragma unroll
    for (int r = 0; r < 2; ++r){
      int c = tid + r * 256;
      int s = c >> 3, gl = c & 7;
      int g = gl ^ (s & 7);
      uint4 v = *(const uint4*)(sigh + (size_t)t * 4096 + s * 64 + g * 8);
      *(uint4*)(&sbuf[b][c * 8]) = v;
    }
  };

  float v1[4], v2[4]; int j1[4], j2[4];
  #pragma unroll
  for (int r = 0; r < 4; ++r){ v1[r] = -3e38f; v2[r] = -3e38f; j1[r] = 0; j2[r] = 0; }

  const int swz = lm & 7;
  stage(0, 0);
  for (int t = 0; t < 16; ++t){
    __syncthreads();
    if (t + 1 < 16) stage(t + 1, (t + 1) & 1);
    const u16* buf = sbuf[t & 1];
    #pragma unroll
    for (int ss = 0; ss < 4; ++ss){
      int srow = ss * 16 + lm;               // slot within tile (B-frag n = lm)
      int c0 = (quad ^ swz) * 8;
      bf16x8 b0 = *(const bf16x8*)(&buf[srow * 64 + c0]);
      bf16x8 b1 = *(const bf16x8*)(&buf[srow * 64 + (c0 ^ 32)]);  // chunk^4 -> +-32 u16
      f32x4 acc = {0.f, 0.f, 0.f, 0.f};
      acc = __builtin_amdgcn_mfma_f32_16x16x32_bf16(a0, b0, acc, 0, 0, 0);
      acc = __builtin_amdgcn_mfma_f32_16x16x32_bf16(a1, b1, acc, 0, 0, 0);
      int sidx = t * 64 + srow;
      #pragma unroll
      for (int r = 0; r < 4; ++r){
        float v = acc[r];
        bool g1 = v > v1[r];
        bool g2 = v > v2[r];
        float nv2 = g1 ? v1[r] : (g2 ? v : v2[r]);
        int   nj2 = g1 ? j1[r] : (g2 ? sidx : j2[r]);
        v2[r] = nv2; j2[r] = nj2;
        v1[r] = g1 ? v : v1[r];
        j1[r] = g1 ? sidx : j1[r];
      }
    }
  }
  // butterfly merge across the 16 lm-lanes (candidates for token quad*4+r)
  #pragma unroll
  for (int off = 1; off < 16; off <<= 1){
    #pragma unroll
    for (int r = 0; r < 4; ++r){
      float ov1 = __shfl_xor(v1[r], off);
      int   oj1 = __shfl_xor(j1[r], off);
      float ov2 = __shfl_xor(v2[r], off);
      int   oj2 = __shfl_xor(j2[r], off);
      bool gt = ov1 > v1[r];
      float ca = gt ? v1[r] : ov1; int cja = gt ? j1[r] : oj1;
      float cb = gt ? ov2  : v2[r]; int cjb = gt ? oj2  : j2[r];
      v1[r] = gt ? ov1 : v1[r];  j1[r] = gt ? oj1 : j1[r];
      bool gb = cb > ca;
      v2[r] = gb ? cb : ca;  j2[r] = gb ? cjb : cja;
    }
  }
  if (lm == 0){
    float tsc = 1.0f / (temp[0] * 8.0f);     // 1/(temperature*sqrt(64))
    #pragma unroll
    for (int r = 0; r < 4; ++r){
      int tok = w * 16 + quad * 4 + r;
      float ex = expf((v2[r] - v1[r]) * tsc);  // <= 1, stable
      float iw = 1.0f / (1.0f + ex);
      fw1[tok] = iw; fw2[tok] = ex * iw;
      fi1[tok] = j1[r]; fi2[tok] = j2[r];
    }
  }
  __syncthreads();
  // gather: token = tid>>2, dims [(tid&3)*16, +16)
  int tok = tid >> 2, d0 = (tid & 3) * 16;
  const float* va = V + ((size_t)h * 1024 + fi1[tok]) * 64 + d0;
  const float* vb = V + ((size_t)h * 1024 + fi2[tok]) * 64 + d0;
  float W1 = fw1[tok], W2 = fw2[tok];
  u32 pk[8];
  #pragma unroll
  for (int d = 0; d < 16; d += 4){
    f32x4 x1 = *(const f32x4*)(va + d);
    f32x4 x2 = *(const f32x4*)(vb + d);
    #pragma unroll
    for (int e = 0; e < 4; e += 2){
      float y0 = W1 * x1[e]     + W2 * x2[e];
      float y1 = W1 * x1[e + 1] + W2 * x2[e + 1];
      pk[(d + e) >> 1] = (u32)f2bf(y0) | ((u32)f2bf(y1) << 16);
    }
  }
  u16* dst = rd + (size_t)(t0 + tok) * 1024 + h * 64 + d0;
  uint4 o0 = {pk[0], pk[1], pk[2], pk[3]};
  uint4 o1 = {pk[4], pk[5], pk[6], pk[7]};
  *(uint4*)dst = o0;
  *(uint4*)(dst + 8) = o1;
}

extern "C" void kernel_launch(void* const* d_in, const int* in_sizes, int n_in,
                              void* d_out, int out_size, void* d_ws, size_t ws_size,
                              hipStream_t stream){
  const float* x    = (const float*)d_in[0];
  const float* lng  = (const float*)d_in[1];
  const float* lnb  = (const float*)d_in[2];
  const float* qw   = (const float*)d_in[3];
  const float* qb   = (const float*)d_in[4];
  const float* sig  = (const float*)d_in[5];
  const float* sv   = (const float*)d_in[6];
  const float* ow   = (const float*)d_in[7];
  const float* ob   = (const float*)d_in[8];
  const float* temp = (const float*)d_in[9];
  float* out = (float*)d_out;

  char* ws = (char*)d_ws;
  u16* xn   = (u16*)(ws);                                  // 16 MiB  (x_norm bf16; reused as `read`)
  u16* qwb  = (u16*)(ws + 16777216);                       //  2 MiB
  u16* owb  = (u16*)(ws + 16777216 + 2097152);             //  2 MiB
  u16* sgb  = (u16*)(ws + 16777216 + 2 * 2097152);         //  2 MiB
  u16* qb16 = (u16*)(ws + 16777216 + 3 * 2097152);         // 16 MiB  (q bf16)
  u16* rdb  = xn;                                          // alias: x_norm dead after GEMM1

  convert_kernel<<<4096, 256, 0, stream>>>(qw, ow, sig, qwb, owb, sgb);
  ln_kernel<<<8192, 256, 0, stream>>>(x, lng, lnb, xn);
  gemm_bt<<<dim3(8, 64), 256, 0, stream>>>(xn, qwb, qb, nullptr, nullptr, qb16, 0);
  route_kernel<<<dim3(128, 16), 256, 0, stream>>>(qb16, sgb, sv, temp, rdb);
  gemm_bt<<<dim3(8, 64), 256, 0, stream>>>(rdb, owb, ob, x, out, nullptr, 1);
}

// Round 3
// 216.954 us; speedup vs baseline: 1.4506x; 1.0349x over previous
//
#include <hip/hip_runtime.h>

typedef unsigned short u16;
typedef unsigned int   u32;
typedef float f32x4  __attribute__((ext_vector_type(4)));
typedef float f32x16 __attribute__((ext_vector_type(16)));
typedef __bf16 bf16x8 __attribute__((ext_vector_type(8)));

__device__ __forceinline__ u16 f2bf(float f){
  u32 u = __float_as_uint(f);
  u += 0x7fffu + ((u >> 16) & 1u);          // RNE
  return (u16)(u >> 16);
}

// async global->LDS, 16B per lane; LDS dest is wave-uniform base + lane*16
__device__ __forceinline__ void gld16(const void* g, void* l){
  __builtin_amdgcn_global_load_lds((const __attribute__((address_space(1))) u32*)g,
                                   (__attribute__((address_space(3))) u32*)l, 16, 0, 0);
}

// ---------------- weight conversion: fp32->bf16, sigs->ternary bf16 ----------------
__global__ __launch_bounds__(256) void convert_kernel(
    const float* __restrict__ qw, const float* __restrict__ ow,
    const float* __restrict__ sg,
    u16* __restrict__ qwb, u16* __restrict__ owb, u16* __restrict__ sgb){
  int i = blockIdx.x * 256 + threadIdx.x;   // 1,048,576 elements each
  qwb[i] = f2bf(qw[i]);
  owb[i] = f2bf(ow[i]);
  float s = sg[i];
  float t = (s > 0.3f) ? 1.0f : ((s < -0.3f) ? -1.0f : 0.0f);
  sgb[i] = f2bf(t);                          // {-1,0,1} exact in bf16
}

// ---------------- LayerNorm: one block per token ----------------
__global__ __launch_bounds__(256) void ln_kernel(
    const float* __restrict__ x, const float* __restrict__ g,
    const float* __restrict__ b, u16* __restrict__ xn){
  const int t = blockIdx.x, tid = threadIdx.x;
  f32x4 v = *(const f32x4*)(x + (size_t)t * 1024 + tid * 4);
  float s  = v[0] + v[1] + v[2] + v[3];
  float ss = v[0]*v[0] + v[1]*v[1] + v[2]*v[2] + v[3]*v[3];
  for (int off = 32; off; off >>= 1){
    s  += __shfl_down(s, off);
    ss += __shfl_down(ss, off);
  }
  __shared__ float red[8];
  int w = tid >> 6;
  if ((tid & 63) == 0){ red[w] = s; red[4 + w] = ss; }
  __syncthreads();
  s  = red[0] + red[1] + red[2] + red[3];
  ss = red[4] + red[5] + red[6] + red[7];
  float mean = s * (1.0f / 1024.0f);
  float var  = ss * (1.0f / 1024.0f) - mean * mean;   // jnp.var (ddof=0)
  float rs   = rsqrtf(var + 1e-5f);
  f32x4 gv = *(const f32x4*)(g + tid * 4);
  f32x4 bv = *(const f32x4*)(b + tid * 4);
  float y0 = (v[0]-mean)*rs*gv[0]+bv[0];
  float y1 = (v[1]-mean)*rs*gv[1]+bv[1];
  float y2 = (v[2]-mean)*rs*gv[2]+bv[2];
  float y3 = (v[3]-mean)*rs*gv[3]+bv[3];
  uint2 pk;
  pk.x = (u32)f2bf(y0) | ((u32)f2bf(y1) << 16);
  pk.y = (u32)f2bf(y2) | ((u32)f2bf(y3) << 16);
  *(uint2*)(xn + (size_t)t * 1024 + tid * 4) = pk;
}

// ---------------- bf16 MFMA GEMM: C[m,n] = sum_k A[m,k]*B[n,k] (+epilogue) ----------------
// M=8192, N=1024, K=1024. 128x128 tile, 4 waves in 2x2, each wave 64x64 (4x4 MFMA 16x16x32).
// LDS unpadded 64-u16 stride, XOR-swizzled: chunk g (16B) of row s lives at position g^(s&7).
// Staged via global_load_lds (lane-linear dest); swizzle applied on the SOURCE address.
// mode 0: outb[m,n] = bf16(C + bias[n]);  mode 1: outf[m,n] = C + bias[n] + resid[m,n]
__global__ __launch_bounds__(256, 2) void gemm_bt(
    const u16* __restrict__ A, const u16* __restrict__ B,
    const float* __restrict__ bias, const float* __restrict__ resid,
    float* __restrict__ outf, u16* __restrict__ outb, int mode){
  __shared__ u16 As[128 * 64];      // 16 KB
  __shared__ u16 Bs[128 * 64];
  const int tid = threadIdx.x;
  const int m0 = blockIdx.y * 128, n0 = blockIdx.x * 128;
  const int w = tid >> 6, lane = tid & 63, lm = lane & 15, quad = lane >> 4;
  const int wm = (w & 1) * 64, wn = (w >> 1) * 64;
  const int lr = lane >> 3;                 // row-within-8 of this lane's staging chunk
  const int lg = (lane & 7) ^ lr;           // swizzled source chunk id
  const f32x4 fz = {0.f, 0.f, 0.f, 0.f};
  f32x4 acc[4][4];
  #pragma unroll
  for (int i = 0; i < 4; ++i)
    #pragma unroll
    for (int j = 0; j < 4; ++j) acc[i][j] = fz;

  const u16* gA = A + (size_t)(m0 + w * 32 + lr) * 1024 + lg * 8;
  const u16* gB = B + (size_t)(n0 + w * 32 + lr) * 1024 + lg * 8;
  u16* lA = &As[(w * 32) * 64];             // wave-uniform LDS bases
  u16* lB = &Bs[(w * 32) * 64];
  const int sw = lm & 7;

  for (int kt = 0; kt < 16; ++kt){
    #pragma unroll
    for (int sub = 0; sub < 4; ++sub){
      gld16(gA + (size_t)(sub * 8) * 1024 + kt * 64, lA + sub * 8 * 64);
      gld16(gB + (size_t)(sub * 8) * 1024 + kt * 64, lB + sub * 8 * 64);
    }
    __syncthreads();
    #pragma unroll
    for (int kk = 0; kk < 2; ++kk){
      const int ch = ((quad + kk * 4) ^ sw) * 8;   // swizzled chunk offset (u16)
      bf16x8 afr[4], bfr[4];
      #pragma unroll
      for (int i = 0; i < 4; ++i)
        afr[i] = *(const bf16x8*)(&As[(wm + i * 16 + lm) * 64 + ch]);
      #pragma unroll
      for (int j = 0; j < 4; ++j)
        bfr[j] = *(const bf16x8*)(&Bs[(wn + j * 16 + lm) * 64 + ch]);
      #pragma unroll
      for (int i = 0; i < 4; ++i)
        #pragma unroll
        for (int j = 0; j < 4; ++j)
          acc[i][j] = __builtin_amdgcn_mfma_f32_16x16x32_bf16(afr[i], bfr[j], acc[i][j], 0, 0, 0);
    }
    __syncthreads();
  }

  #pragma unroll
  for (int i = 0; i < 4; ++i){
    #pragma unroll
    for (int r = 0; r < 4; ++r){
      int grow = m0 + wm + i * 16 + quad * 4 + r;
      #pragma unroll
      for (int j = 0; j < 4; ++j){
        int gcol = n0 + wn + j * 16 + lm;
        float v = acc[i][j][r] + bias[gcol];
        if (mode){
          v += resid[(size_t)grow * 1024 + gcol];
          outf[(size_t)grow * 1024 + gcol] = v;
        } else {
          outb[(size_t)grow * 1024 + gcol] = f2bf(v);
        }
      }
    }
  }
}

// ---------------- fused scores + top2 + softmax + gather ----------------
// block = 128 tokens x 1 head; 4 waves, wave w owns tokens [w*32, w*32+32).
// 32x32x16 MFMA: per wave-iteration 1024 scores from 4 MFMAs.
// Top-2 via key packing: slot index lives in the low 10 mantissa bits of the
// fp32 score (<=2^-13 relative perturbation); update = and_or + max + med3.
// sig tile (128 slots, 16KB) double-buffered in LDS, XOR-swizzled.
__global__ __launch_bounds__(256) void route_kernel(
    const u16* __restrict__ q, const u16* __restrict__ sig,
    const float* __restrict__ V, const float* __restrict__ temp,
    u16* __restrict__ rd){
  const int h = blockIdx.y;
  const int t0 = blockIdx.x * 128;
  const int tid = threadIdx.x, w = tid >> 6, lane = tid & 63;
  const int col = lane & 31, half = lane >> 5;

  __shared__ u16 sbuf[2][128 * 64];         // 2 x 16 KB, swizzled
  __shared__ float fw1[128], fw2[128];
  __shared__ int   fi1[128], fi2[128];

  // A fragments: token m = t0 + w*32 + col; chunk c holds k = c*16 + half*8 + j
  const u16* qrow = q + (size_t)(t0 + w * 32 + col) * 1024 + h * 64 + half * 8;
  bf16x8 afr[4];
  #pragma unroll
  for (int c = 0; c < 4; ++c) afr[c] = *(const bf16x8*)(qrow + c * 16);

  const u16* sigh = sig + (size_t)h * 65536;

  // staging: wave w stages rows [w*32, w*32+32) of the 128-slot tile.
  // 8 lanes per row (16B chunks); swizzle: LDS pos p of row s holds chunk p^(s&7).
  const int lr = lane >> 3, lg = (lane & 7) ^ lr;
  const u16* ssrc = sigh + (size_t)(w * 32 + lr) * 64 + lg * 8;
  auto stage = [&](int t, int b){
    const u16* s0 = ssrc + (size_t)t * 128 * 64;
    u16* d0 = &sbuf[b][(w * 32) * 64];
    #pragma unroll
    for (int sub = 0; sub < 4; ++sub)
      gld16(s0 + sub * 8 * 64, d0 + sub * 8 * 64);
  };

  // loop-invariant swizzled read offsets (u16 units): chunk c2 = c*2+half of row col
  int p0 = ((0 + half) ^ (col & 7)) * 8;
  int p1 = ((2 + half) ^ (col & 7)) * 8;
  int p2 = ((4 + half) ^ (col & 7)) * 8;
  int p3 = ((6 + half) ^ (col & 7)) * 8;

  float v1[16], v2[16];
  #pragma unroll
  for (int r = 0; r < 16; ++r){ v1[r] = -3.0e38f; v2[r] = -3.0e38f; }

  stage(0, 0);
  for (int t = 0; t < 8; ++t){
    __syncthreads();                         // drains vmcnt: staging of buf t&1 visible
    if (t < 7) stage(t + 1, (t + 1) & 1);
    const u16* buf = sbuf[t & 1];
    #pragma unroll
    for (int sbl = 0; sbl < 4; ++sbl){
      const u16* srow = &buf[(sbl * 32 + col) * 64];
      bf16x8 b0 = *(const bf16x8*)(srow + p0);
      bf16x8 b1 = *(const bf16x8*)(srow + p1);
      bf16x8 b2 = *(const bf16x8*)(srow + p2);
      bf16x8 b3 = *(const bf16x8*)(srow + p3);
      f32x16 acc = {};
      acc = __builtin_amdgcn_mfma_f32_32x32x16_bf16(afr[0], b0, acc, 0, 0, 0);
      acc = __builtin_amdgcn_mfma_f32_32x32x16_bf16(afr[1], b1, acc, 0, 0, 0);
      acc = __builtin_amdgcn_mfma_f32_32x32x16_bf16(afr[2], b2, acc, 0, 0, 0);
      acc = __builtin_amdgcn_mfma_f32_32x32x16_bf16(afr[3], b3, acc, 0, 0, 0);
      u32 sidx = (u32)(t * 128 + sbl * 32 + col);
      #pragma unroll
      for (int r = 0; r < 16; ++r){
        u32 u = __float_as_uint(acc[r]);
        float key = __uint_as_float((u & 0xFFFFFC00u) | sidx);
        float o1 = v1[r];
        v1[r] = fmaxf(o1, key);
        v2[r] = __builtin_amdgcn_fmed3f(o1, v2[r], key);
      }
    }
  }

  // butterfly merge across the 32 cols (each lane-group holds same 16 token rows)
  #pragma unroll
  for (int off = 1; off < 32; off <<= 1){
    #pragma unroll
    for (int r = 0; r < 16; ++r){
      float b1v = __shfl_xor(v1[r], off);
      float b2v = __shfl_xor(v2[r], off);
      float a1 = v1[r];
      v1[r] = fmaxf(a1, b1v);
      v2[r] = __builtin_amdgcn_fmed3f(a1, b1v, fmaxf(v2[r], b2v));
    }
  }

  if (col == 0){                             // lanes 0 and 32 of each wave
    float tsc = 1.0f / (temp[0] * 8.0f);     // 1/(temperature*sqrt(64))
    #pragma unroll
    for (int r = 0; r < 16; ++r){
      int row = (r & 3) + 8 * (r >> 2) + 4 * half;   // verified 32x32 C/D row map
      int tl = w * 32 + row;
      u32 u1 = __float_as_uint(v1[r]);
      u32 u2 = __float_as_uint(v2[r]);
      float s1 = __uint_as_float(u1 & 0xFFFFFC00u);
      float s2 = __uint_as_float(u2 & 0xFFFFFC00u);
      float ex = __expf((s2 - s1) * tsc);    // <= 1, stable
      float iw = 1.0f / (1.0f + ex);
      fw1[tl] = iw; fw2[tl] = ex * iw;
      fi1[tl] = (int)(u1 & 1023u); fi2[tl] = (int)(u2 & 1023u);
    }
  }
  __syncthreads();

  // gather: token = tid>>1, dims [(tid&1)*32, +32)
  int tl = tid >> 1, d0 = (tid & 1) * 32;
  const float* va = V + ((size_t)h * 1024 + fi1[tl]) * 64 + d0;
  const float* vb = V + ((size_t)h * 1024 + fi2[tl]) * 64 + d0;
  float W1 = fw1[tl], W2 = fw2[tl];
  u16* dst = rd + (size_t)(t0 + tl) * 1024 + h * 64 + d0;
  #pragma unroll
  for (int g = 0; g < 4; ++g){
    f32x4 xa = *(const f32x4*)(va + g * 8);
    f32x4 xb = *(const f32x4*)(va + g * 8 + 4);
    f32x4 ya = *(const f32x4*)(vb + g * 8);
    f32x4 yb = *(const f32x4*)(vb + g * 8 + 4);
    uint4 o;
    o.x = (u32)f2bf(W1*xa[0]+W2*ya[0]) | ((u32)f2bf(W1*xa[1]+W2*ya[1]) << 16);
    o.y = (u32)f2bf(W1*xa[2]+W2*ya[2]) | ((u32)f2bf(W1*xa[3]+W2*ya[3]) << 16);
    o.z = (u32)f2bf(W1*xb[0]+W2*yb[0]) | ((u32)f2bf(W1*xb[1]+W2*yb[1]) << 16);
    o.w = (u32)f2bf(W1*xb[2]+W2*yb[2]) | ((u32)f2bf(W1*xb[3]+W2*yb[3]) << 16);
    *(uint4*)(dst + g * 8) = o;
  }
}

extern "C" void kernel_launch(void* const* d_in, const int* in_sizes, int n_in,
                              void* d_out, int out_size, void* d_ws, size_t ws_size,
                              hipStream_t stream){
  const float* x    = (const float*)d_in[0];
  const float* lng  = (const float*)d_in[1];
  const float* lnb  = (const float*)d_in[2];
  const float* qw   = (const float*)d_in[3];
  const float* qb   = (const float*)d_in[4];
  const float* sig  = (const float*)d_in[5];
  const float* sv   = (const float*)d_in[6];
  const float* ow   = (const float*)d_in[7];
  const float* ob   = (const float*)d_in[8];
  const float* temp = (const float*)d_in[9];
  float* out = (float*)d_out;

  char* ws = (char*)d_ws;
  u16* xn   = (u16*)(ws);                                  // 16 MiB  (x_norm bf16; reused as `read`)
  u16* qwb  = (u16*)(ws + 16777216);                       //  2 MiB
  u16* owb  = (u16*)(ws + 16777216 + 2097152);             //  2 MiB
  u16* sgb  = (u16*)(ws + 16777216 + 2 * 2097152);         //  2 MiB
  u16* qb16 = (u16*)(ws + 16777216 + 3 * 2097152);         // 16 MiB  (q bf16)
  u16* rdb  = xn;                                          // alias: x_norm dead after GEMM1

  convert_kernel<<<4096, 256, 0, stream>>>(qw, ow, sig, qwb, owb, sgb);
  ln_kernel<<<8192, 256, 0, stream>>>(x, lng, lnb, xn);
  gemm_bt<<<dim3(8, 64), 256, 0, stream>>>(xn, qwb, qb, nullptr, nullptr, qb16, 0);
  route_kernel<<<dim3(64, 16), 256, 0, stream>>>(qb16, sgb, sv, temp, rdb);
  gemm_bt<<<dim3(8, 64), 256, 0, stream>>>(rdb, owb, ob, x, out, nullptr, 1);
}